// Round 2
// baseline (1779.413 us; speedup 1.0000x reference)
//
#include <hip/hip_runtime.h>
#include <hip/hip_bf16.h>
#include <stdint.h>

typedef unsigned short u16;
typedef __attribute__((ext_vector_type(4))) float f32x4;
typedef __attribute__((ext_vector_type(8))) short s16x8;

// ---------- helpers ----------

static __device__ __forceinline__ u16 f2bf(float f) {
  union { float f; unsigned u; } v; v.f = f;
  unsigned r = v.u + 0x7FFFu + ((v.u >> 16) & 1u);
  return (u16)(r >> 16);
}

static __device__ __forceinline__ void gload_lds16(const void* g, void* l) {
  __builtin_amdgcn_global_load_lds(
      (const __attribute__((address_space(1))) unsigned int*)(uintptr_t)g,
      (__attribute__((address_space(3))) unsigned int*)(uintptr_t)l,
      16, 0, 0);
}

// centralized grid barrier: 1 atomicAdd per WG, poll a single seq word.
// cnt accumulates monotonically (step*nwg at completion of step).
static __device__ __forceinline__ void grid_bar(int* cnt, int* seq, int step, int nwg) {
  __syncthreads();
  if (threadIdx.x == 0) {
    __builtin_amdgcn_fence(__ATOMIC_RELEASE, "agent");
    int old = __hip_atomic_fetch_add(cnt, 1, __ATOMIC_ACQ_REL, __HIP_MEMORY_SCOPE_AGENT);
    if (old == step * nwg - 1) {
      __hip_atomic_store(seq, step, __ATOMIC_RELEASE, __HIP_MEMORY_SCOPE_AGENT);
    } else {
      int c = 0;
      while (__hip_atomic_load(seq, __ATOMIC_ACQUIRE, __HIP_MEMORY_SCOPE_AGENT) < step) {
        __builtin_amdgcn_s_sleep(1);
        if (++c > (1 << 20)) break;   // safety: never hang the harness
      }
    }
  }
  __syncthreads();
  __builtin_amdgcn_fence(__ATOMIC_ACQUIRE, "agent");
}

// ---------- pre-pass kernels ----------

__global__ void embed_kernel(const int* __restrict__ inputs,
                             const float* __restrict__ emb,
                             u16* __restrict__ xbf) {
  int i = blockIdx.x * 256 + threadIdx.x;   // 131072 threads
  int row = i >> 6;
  int e0 = (i & 63) << 3;
  int tok = inputs[row];
  const float* src = emb + (size_t)tok * 512 + e0;
  s16x8 o;
#pragma unroll
  for (int j = 0; j < 8; ++j) o[j] = (short)f2bf(src[j]);
  *(s16x8*)(xbf + (size_t)row * 512 + e0) = o;
}

// Wt[n][k] = bf16(W[k][n]); K,N multiples of 32
__global__ void transpose_bf16(const float* __restrict__ W, u16* __restrict__ Wt,
                               int K, int N) {
  __shared__ float t[32][33];
  int ntn = N >> 5;
  int tn = blockIdx.x % ntn, tk = blockIdx.x / ntn;
  int n0 = tn << 5, k0 = tk << 5;
  int tx = threadIdx.x & 31, ty = threadIdx.x >> 5;  // ty 0..7
#pragma unroll
  for (int j = 0; j < 4; ++j) {
    int k = ty * 4 + j;
    t[k][tx] = W[(size_t)(k0 + k) * N + n0 + tx];
  }
  __syncthreads();
#pragma unroll
  for (int j = 0; j < 4; ++j) {
    int n = ty * 4 + j;
    Wt[(size_t)(n0 + n) * K + k0 + tx] = f2bf(t[tx][n]);
  }
}

// ---------- m97-style bf16 GEMM, 128x128 tile, BK=32 ----------
// MODE 0: C=f32, store acc+bias          (xg)
// MODE 1: C=bf16, store relu(acc+bias)   (d1)
// MODE 2: C=f32, store exp(acc+bias), atomicAdd row sums (logits->exp)
template <int MODE>
__global__ __launch_bounds__(256)
void gemm_bf16(const u16* __restrict__ A, const u16* __restrict__ Bt,
               const float* __restrict__ bias, void* __restrict__ Cptr,
               float* __restrict__ rowsum, int M, int N, int K) {
  (void)M;
  __shared__ u16 sA[128 * 32];
  __shared__ u16 sB[128 * 32];
  const int nbn = N >> 7;
  const int nwg = gridDim.x;
  int bid = blockIdx.x;
  int q = nwg >> 3;                         // grids are multiples of 8
  int swz = (bid & 7) * q + (bid >> 3);     // XCD-aware swizzle (bijective)
  int bm = swz / nbn, bn = swz % nbn;
  const int brow = bm << 7, bcol = bn << 7;

  const int tid = threadIdx.x;
  const int lane = tid & 63;
  const int wv = tid >> 6;
  const int wr = (wv >> 1) * 64, wc = (wv & 1) * 64;
  const int ln = lane & 15, kh = lane >> 4;

  const int srow = tid >> 2;                // 0..63
  const int kch = (tid & 3) << 3;           // 0,8,16,24 (elements)

  f32x4 acc[4][4] = {};

  const int nk = K >> 5;
  const u16* Abase = A + (size_t)(brow + srow) * K + kch;
  const u16* Bbase = Bt + (size_t)(bcol + srow) * K + kch;
  const size_t rstride = (size_t)64 * K;
  u16* lA = sA + srow * 32 + kch;
  u16* lB = sB + srow * 32 + kch;

  for (int kt = 0; kt < nk; ++kt) {
    const int k0 = kt << 5;
    gload_lds16(Abase + k0, lA);
    gload_lds16(Abase + rstride + k0, lA + 64 * 32);
    gload_lds16(Bbase + k0, lB);
    gload_lds16(Bbase + rstride + k0, lB + 64 * 32);
    __syncthreads();
    s16x8 aF[4], bF[4];
#pragma unroll
    for (int m = 0; m < 4; ++m)
      aF[m] = *(const s16x8*)(sA + (wr + m * 16 + ln) * 32 + kh * 8);
#pragma unroll
    for (int n = 0; n < 4; ++n)
      bF[n] = *(const s16x8*)(sB + (wc + n * 16 + ln) * 32 + kh * 8);
#pragma unroll
    for (int m = 0; m < 4; ++m)
#pragma unroll
      for (int n = 0; n < 4; ++n)
        acc[m][n] = __builtin_amdgcn_mfma_f32_16x16x32_bf16(aF[m], bF[n], acc[m][n], 0, 0, 0);
    __syncthreads();
  }

  const int browq = brow + wr;
  const int bcolq = bcol + wc;

  if (MODE == 1) {
    u16* O = (u16*)Cptr;
#pragma unroll
    for (int n = 0; n < 4; ++n) {
      int gcol = bcolq + n * 16 + ln;
      float bv = bias[gcol];
#pragma unroll
      for (int m = 0; m < 4; ++m)
#pragma unroll
        for (int r = 0; r < 4; ++r) {
          int grow = browq + m * 16 + kh * 4 + r;
          float v = fmaxf(acc[m][n][r] + bv, 0.f);
          O[(size_t)grow * N + gcol] = f2bf(v);
        }
    }
  } else {
    float* O = (float*)Cptr;
    float rs[4][4] = {};
#pragma unroll
    for (int n = 0; n < 4; ++n) {
      int gcol = bcolq + n * 16 + ln;
      float bv = bias[gcol];
#pragma unroll
      for (int m = 0; m < 4; ++m)
#pragma unroll
        for (int r = 0; r < 4; ++r) {
          int grow = browq + m * 16 + kh * 4 + r;
          float v = acc[m][n][r] + bv;
          if (MODE == 2) { v = __expf(v); rs[m][r] += v; }
          O[(size_t)grow * N + gcol] = v;
        }
    }
    if (MODE == 2) {
#pragma unroll
      for (int m = 0; m < 4; ++m)
#pragma unroll
        for (int r = 0; r < 4; ++r) {
          float v = rs[m][r];
          v += __shfl_xor(v, 1);
          v += __shfl_xor(v, 2);
          v += __shfl_xor(v, 4);
          v += __shfl_xor(v, 8);
          if (ln == 0) atomicAdd(&rowsum[browq + m * 16 + kh * 4 + r], v);
        }
    }
  }
}

// ---------- persistent LSTM kernel: 64 WGs, Wh weight-stationary in LDS ----------
__global__ __launch_bounds__(256)
void lstm_kernel(const float* __restrict__ xg,      // [2048][4096] f32
                 const u16* __restrict__ Wht,       // [4096][1024] bf16 (n-major)
                 const int* __restrict__ inputs,    // [16][128]
                 const float* __restrict__ ench, const float* __restrict__ encc,
                 const float* __restrict__ gamma, const float* __restrict__ beta,
                 const float* __restrict__ mmean, const float* __restrict__ mvar,
                 u16* __restrict__ hbuf,            // [2][16][1024] bf16
                 u16* __restrict__ hbn,             // [2048][1024] bf16 out (BN applied)
                 int* __restrict__ cnt, int* __restrict__ seq) {
  __shared__ u16 sWh[64 * 1024];       // 128KB, XOR-swizzled 16B chunks
  __shared__ float zx[4][16][16];

  const int wg = blockIdx.x;
  const int u0 = wg << 4;
  const int tid = threadIdx.x;
  const int lane = tid & 63;
  const int wv = tid >> 6;
  const int ln = lane & 15, kh = lane >> 4;

  // stage Wh slice: local row lr = g*16+ul -> global n = g*1024+u0+ul
#pragma unroll
  for (int it = 0; it < 32; ++it) {
    int idx = it * 256 + tid;          // 0..8191 (64 rows x 128 chunks)
    int lr = idx >> 7;
    int ch = idx & 127;
    int g = lr >> 4, ul = lr & 15;
    const u16* src = Wht + (size_t)(g * 1024 + u0 + ul) * 1024 + ch * 8;
    s16x8 v = *(const s16x8*)src;
    int dstB = lr * 2048 + ((ch * 16) ^ ((lr & 7) << 4));
    *(s16x8*)((char*)sWh + dstB) = v;
  }

  const int b0 = tid >> 4, ulT = tid & 15, uT = u0 + ulT;
  float cellR = encc[b0 * 1024 + uT];
  float holdR = ench[b0 * 1024 + uT];
  hbuf[b0 * 1024 + uT] = f2bf(holdR);
  float bn_s = gamma[uT] * rsqrtf(mvar[uT] + 1e-3f);
  float bn_b = beta[uT] - mmean[uT] * bn_s;

  // prefetch xg(0) and inputs(0) into registers
  const size_t bstride = (size_t)128 * 4096;
  const float* xbase = xg + (size_t)(kh * 4) * bstride + wv * 1024 + u0 + ln;
  float xgr0 = xbase[0];
  float xgr1 = xbase[bstride];
  float xgr2 = xbase[2 * bstride];
  float xgr3 = xbase[3 * bstride];
  int inpv = inputs[b0 * 128];

  grid_bar(cnt, seq, 1, 64);

  const int lr = wv * 16 + ln;
  const int swzrow = lr * 2048;
  const int swzx = (lr & 7) << 4;

  for (int s = 0; s < 128; ++s) {
    const u16* hsrc = hbuf + (s & 1) * 16384;
    // two accumulator chains to halve MFMA dependency latency
    f32x4 acc0 = {0.f, 0.f, 0.f, 0.f};
    f32x4 acc1 = {0.f, 0.f, 0.f, 0.f};
#pragma unroll 8
    for (int kt = 0; kt < 32; kt += 2) {
      s16x8 a0 = *(const s16x8*)(hsrc + ln * 1024 + kt * 32 + kh * 8);
      s16x8 b0v = *(const s16x8*)((const char*)sWh + swzrow + ((kt * 64 + kh * 16) ^ swzx));
      acc0 = __builtin_amdgcn_mfma_f32_16x16x32_bf16(a0, b0v, acc0, 0, 0, 0);
      s16x8 a1 = *(const s16x8*)(hsrc + ln * 1024 + (kt + 1) * 32 + kh * 8);
      s16x8 b1v = *(const s16x8*)((const char*)sWh + swzrow + (((kt + 1) * 64 + kh * 16) ^ swzx));
      acc1 = __builtin_amdgcn_mfma_f32_16x16x32_bf16(a1, b1v, acc1, 0, 0, 0);
    }
    f32x4 accs = acc0 + acc1;
    zx[wv][kh * 4 + 0][ln] = accs[0] + xgr0;
    zx[wv][kh * 4 + 1][ln] = accs[1] + xgr1;
    zx[wv][kh * 4 + 2][ln] = accs[2] + xgr2;
    zx[wv][kh * 4 + 3][ln] = accs[3] + xgr3;
    __syncthreads();
    {
      float zi = zx[0][b0][ulT], zf = zx[1][b0][ulT];
      float zc = zx[2][b0][ulT], zo = zx[3][b0][ulT];
      float ig = 1.f / (1.f + __expf(-zi));
      float fg = 1.f / (1.f + __expf(-zf));
      float og = 1.f / (1.f + __expf(-zo));
      float cc = fmaxf(zc, 0.f);
      float cnew = fg * cellR + ig * cc;
      float hnew = og * fmaxf(cnew, 0.f);
      if (inpv == 0) { cnew = cellR; hnew = holdR; }
      cellR = cnew;
      holdR = hnew;
      hbuf[((s + 1) & 1) * 16384 + b0 * 1024 + uT] = f2bf(hnew);
      hbn[(size_t)(b0 * 128 + s) * 1024 + uT] = f2bf(hnew * bn_s + bn_b);
    }
    if (s < 127) {
      // prefetch next step's xg and mask into registers (hidden under barrier wait)
      const float* xb = xbase + (s + 1) * 4096;
      xgr0 = xb[0];
      xgr1 = xb[bstride];
      xgr2 = xb[2 * bstride];
      xgr3 = xb[3 * bstride];
      inpv = inputs[b0 * 128 + s + 1];
      grid_bar(cnt, seq, s + 2, 64);
    }
  }
}

// ---------- softmax finish ----------

__global__ void rcp_kernel(float* rs) {
  int i = blockIdx.x * 256 + threadIdx.x;   // 2048 threads
  rs[i] = 1.0f / rs[i];
}

__global__ void scale_kernel(float* __restrict__ out, const float* __restrict__ rinv) {
  const int total4 = 16384000;              // 65,536,000 / 4
  for (int i = blockIdx.x * 256 + threadIdx.x; i < total4; i += gridDim.x * 256) {
    float4* p = (float4*)out + i;
    float4 v = *p;
    int row = i / 8000;                     // 8000 float4 per row
    float sF = rinv[row];
    v.x *= sF; v.y *= sF; v.z *= sF; v.w *= sF;
    *p = v;
  }
}

// ---------- launch ----------

extern "C" void kernel_launch(void* const* d_in, const int* in_sizes, int n_in,
                              void* d_out, int out_size, void* d_ws, size_t ws_size,
                              hipStream_t stream) {
  (void)in_sizes; (void)n_in; (void)out_size;
  const int*   inputs = (const int*)d_in[0];
  const float* ench   = (const float*)d_in[1];
  const float* encc   = (const float*)d_in[2];
  const float* emb    = (const float*)d_in[3];
  const float* Wx     = (const float*)d_in[4];
  const float* Wh     = (const float*)d_in[5];
  const float* bb     = (const float*)d_in[6];
  const float* gamma  = (const float*)d_in[7];
  const float* beta   = (const float*)d_in[8];
  const float* mmean  = (const float*)d_in[9];
  const float* mvar   = (const float*)d_in[10];
  const float* W1     = (const float*)d_in[11];
  const float* b1     = (const float*)d_in[12];
  const float* W2     = (const float*)d_in[13];
  const float* b2     = (const float*)d_in[14];
  float* out = (float*)d_out;

  char* p = (char*)d_ws;
  size_t off = 0;
  int*   cnt    = (int*)(p + 0);            // word 0
  int*   seq    = (int*)(p + 128);          // separate cache line
  float* rowsum = (float*)(p + 1024);       // 2048 floats; memset covers [0,9216)
  off = 16384;
  u16*   hbuf = (u16*)(p + off);     off += 2 * 16 * 1024 * 2;          // 64KB
  off = 81920;
  u16*   xbf  = (u16*)(p + off);     off += (size_t)2048 * 512 * 2;     // 2MB
  u16*   Wxt  = (u16*)(p + off);     off += (size_t)4096 * 512 * 2;     // 4MB
  u16*   Wht  = (u16*)(p + off);     off += (size_t)4096 * 1024 * 2;    // 8MB
  u16*   W1t  = (u16*)(p + off);     off += (size_t)1024 * 1024 * 2;    // 2MB
  u16*   W2t  = (u16*)(p + off);     off += (size_t)32000 * 1024 * 2;   // 64MB
  float* xg   = (float*)(p + off);   off += (size_t)2048 * 4096 * 4;    // 32MB
  u16*   hbn  = (u16*)(p + off);     off += (size_t)2048 * 1024 * 2;    // 4MB
  u16*   d1   = (u16*)(p + off);     off += (size_t)2048 * 1024 * 2;    // 4MB
  if (ws_size < off) return;  // insufficient scratch; avoid OOB

  hipMemsetAsync(d_ws, 0, 9216, stream);  // cnt + seq + rowsum

  embed_kernel<<<512, 256, 0, stream>>>(inputs, emb, xbf);
  transpose_bf16<<<(512 / 32) * (4096 / 32), 256, 0, stream>>>(Wx, Wxt, 512, 4096);
  transpose_bf16<<<(1024 / 32) * (4096 / 32), 256, 0, stream>>>(Wh, Wht, 1024, 4096);
  transpose_bf16<<<(1024 / 32) * (1024 / 32), 256, 0, stream>>>(W1, W1t, 1024, 1024);
  transpose_bf16<<<(1024 / 32) * (32000 / 32), 256, 0, stream>>>(W2, W2t, 1024, 32000);

  gemm_bf16<0><<<16 * 32, 256, 0, stream>>>(xbf, Wxt, bb, xg, nullptr, 2048, 4096, 512);

  lstm_kernel<<<64, 256, 0, stream>>>(xg, Wht, inputs, ench, encc, gamma, beta,
                                      mmean, mvar, hbuf, hbn, cnt, seq);

  gemm_bf16<1><<<16 * 8, 256, 0, stream>>>(hbn, W1t, b1, d1, nullptr, 2048, 1024, 1024);
  gemm_bf16<2><<<16 * 250, 256, 0, stream>>>(d1, W2t, b2, out, rowsum, 2048, 32000, 1024);

  rcp_kernel<<<8, 256, 0, stream>>>(rowsum);
  scale_kernel<<<2048, 256, 0, stream>>>(out, rowsum);
}

// Round 3
// 1677.393 us; speedup vs baseline: 1.0608x; 1.0608x over previous
//
#include <hip/hip_runtime.h>
#include <hip/hip_bf16.h>
#include <stdint.h>

typedef unsigned short u16;
typedef unsigned int u32;
typedef unsigned long long u64;
typedef __attribute__((ext_vector_type(4))) float f32x4;
typedef __attribute__((ext_vector_type(8))) short s16x8;

// ---------- helpers ----------

static __device__ __forceinline__ u16 f2bf(float f) {
  union { float f; unsigned u; } v; v.f = f;
  unsigned r = v.u + 0x7FFFu + ((v.u >> 16) & 1u);
  return (u16)(r >> 16);
}

static __device__ __forceinline__ void gload_lds16(const void* g, void* l) {
  __builtin_amdgcn_global_load_lds(
      (const __attribute__((address_space(1))) unsigned int*)(uintptr_t)g,
      (__attribute__((address_space(3))) unsigned int*)(uintptr_t)l,
      16, 0, 0);
}

// ---------- pre-pass kernels ----------

__global__ void embed_kernel(const int* __restrict__ inputs,
                             const float* __restrict__ emb,
                             u16* __restrict__ xbf) {
  int i = blockIdx.x * 256 + threadIdx.x;   // 131072 threads
  int row = i >> 6;
  int e0 = (i & 63) << 3;
  int tok = inputs[row];
  const float* src = emb + (size_t)tok * 512 + e0;
  s16x8 o;
#pragma unroll
  for (int j = 0; j < 8; ++j) o[j] = (short)f2bf(src[j]);
  *(s16x8*)(xbf + (size_t)row * 512 + e0) = o;
}

// Wt[n][k] = bf16(W[k][n]); K,N multiples of 32
__global__ void transpose_bf16(const float* __restrict__ W, u16* __restrict__ Wt,
                               int K, int N) {
  __shared__ float t[32][33];
  int ntn = N >> 5;
  int tn = blockIdx.x % ntn, tk = blockIdx.x / ntn;
  int n0 = tn << 5, k0 = tk << 5;
  int tx = threadIdx.x & 31, ty = threadIdx.x >> 5;  // ty 0..7
#pragma unroll
  for (int j = 0; j < 4; ++j) {
    int k = ty * 4 + j;
    t[k][tx] = W[(size_t)(k0 + k) * N + n0 + tx];
  }
  __syncthreads();
#pragma unroll
  for (int j = 0; j < 4; ++j) {
    int n = ty * 4 + j;
    Wt[(size_t)(n0 + n) * K + k0 + tx] = f2bf(t[tx][n]);
  }
}

// ---------- m97-style bf16 GEMM, 128x128 tile, BK=32 ----------
// MODE 0: C=f32, store acc+bias          (xg)
// MODE 1: C=bf16, store relu(acc+bias)   (d1)
// MODE 2: C=f32, store exp(acc+bias), atomicAdd row sums (logits->exp)
template <int MODE>
__global__ __launch_bounds__(256)
void gemm_bf16(const u16* __restrict__ A, const u16* __restrict__ Bt,
               const float* __restrict__ bias, void* __restrict__ Cptr,
               float* __restrict__ rowsum, int M, int N, int K) {
  (void)M;
  __shared__ u16 sA[128 * 32];
  __shared__ u16 sB[128 * 32];
  const int nbn = N >> 7;
  const int nwg = gridDim.x;
  int bid = blockIdx.x;
  int q = nwg >> 3;                         // grids are multiples of 8
  int swz = (bid & 7) * q + (bid >> 3);     // XCD-aware swizzle (bijective)
  int bm = swz / nbn, bn = swz % nbn;
  const int brow = bm << 7, bcol = bn << 7;

  const int tid = threadIdx.x;
  const int lane = tid & 63;
  const int wv = tid >> 6;
  const int wr = (wv >> 1) * 64, wc = (wv & 1) * 64;
  const int ln = lane & 15, kh = lane >> 4;

  const int srow = tid >> 2;                // 0..63
  const int kch = (tid & 3) << 3;           // 0,8,16,24 (elements)

  f32x4 acc[4][4] = {};

  const int nk = K >> 5;
  const u16* Abase = A + (size_t)(brow + srow) * K + kch;
  const u16* Bbase = Bt + (size_t)(bcol + srow) * K + kch;
  const size_t rstride = (size_t)64 * K;
  u16* lA = sA + srow * 32 + kch;
  u16* lB = sB + srow * 32 + kch;

  for (int kt = 0; kt < nk; ++kt) {
    const int k0 = kt << 5;
    gload_lds16(Abase + k0, lA);
    gload_lds16(Abase + rstride + k0, lA + 64 * 32);
    gload_lds16(Bbase + k0, lB);
    gload_lds16(Bbase + rstride + k0, lB + 64 * 32);
    __syncthreads();
    s16x8 aF[4], bF[4];
#pragma unroll
    for (int m = 0; m < 4; ++m)
      aF[m] = *(const s16x8*)(sA + (wr + m * 16 + ln) * 32 + kh * 8);
#pragma unroll
    for (int n = 0; n < 4; ++n)
      bF[n] = *(const s16x8*)(sB + (wc + n * 16 + ln) * 32 + kh * 8);
#pragma unroll
    for (int m = 0; m < 4; ++m)
#pragma unroll
      for (int n = 0; n < 4; ++n)
        acc[m][n] = __builtin_amdgcn_mfma_f32_16x16x32_bf16(aF[m], bF[n], acc[m][n], 0, 0, 0);
    __syncthreads();
  }

  const int browq = brow + wr;
  const int bcolq = bcol + wc;

  if (MODE == 1) {
    u16* O = (u16*)Cptr;
#pragma unroll
    for (int n = 0; n < 4; ++n) {
      int gcol = bcolq + n * 16 + ln;
      float bv = bias[gcol];
#pragma unroll
      for (int m = 0; m < 4; ++m)
#pragma unroll
        for (int r = 0; r < 4; ++r) {
          int grow = browq + m * 16 + kh * 4 + r;
          float v = fmaxf(acc[m][n][r] + bv, 0.f);
          O[(size_t)grow * N + gcol] = f2bf(v);
        }
    }
  } else {
    float* O = (float*)Cptr;
    float rs[4][4] = {};
#pragma unroll
    for (int n = 0; n < 4; ++n) {
      int gcol = bcolq + n * 16 + ln;
      float bv = bias[gcol];
#pragma unroll
      for (int m = 0; m < 4; ++m)
#pragma unroll
        for (int r = 0; r < 4; ++r) {
          int grow = browq + m * 16 + kh * 4 + r;
          float v = acc[m][n][r] + bv;
          if (MODE == 2) { v = __expf(v); rs[m][r] += v; }
          O[(size_t)grow * N + gcol] = v;
        }
    }
    if (MODE == 2) {
#pragma unroll
      for (int m = 0; m < 4; ++m)
#pragma unroll
        for (int r = 0; r < 4; ++r) {
          float v = rs[m][r];
          v += __shfl_xor(v, 1);
          v += __shfl_xor(v, 2);
          v += __shfl_xor(v, 4);
          v += __shfl_xor(v, 8);
          if (ln == 0) atomicAdd(&rowsum[browq + m * 16 + kh * 4 + r], v);
        }
    }
  }
}

// ---------- persistent LSTM kernel: 64 WGs, Wh weight-stationary in LDS ----------
// Cross-WG h exchange uses ONLY relaxed agent-scope atomics (global_* sc0 sc1,
// forced L2-bypass to the coherence point): no release/acquire fences -> no
// buffer_wbl2 / buffer_inv cache-maintenance in the step loop.
__global__ __launch_bounds__(256)
void lstm_kernel(const float* __restrict__ xg,      // [2048][4096] f32
                 const u16* __restrict__ Wht,       // [4096][1024] bf16 (n-major)
                 const int* __restrict__ inputs,    // [16][128]
                 const float* __restrict__ ench, const float* __restrict__ encc,
                 const float* __restrict__ gamma, const float* __restrict__ beta,
                 const float* __restrict__ mmean, const float* __restrict__ mvar,
                 u32* __restrict__ hbuf32,          // [2][16][512] u32 (= 2 bf16 each)
                 u16* __restrict__ hbn,             // [2048][1024] bf16 out (BN applied)
                 int* __restrict__ cnt) {
  __shared__ u16 sWh[64 * 1024];       // 128KB, XOR-swizzled 16B chunks
  __shared__ float zx[4][16][16];
  __shared__ u16 sh[16][16];

  const int wg = blockIdx.x;
  const int u0 = wg << 4;
  const int tid = threadIdx.x;
  const int lane = tid & 63;
  const int wv = tid >> 6;
  const int ln = lane & 15, kh = lane >> 4;

  // stage Wh slice: local row lr = g*16+ul -> global n = g*1024+u0+ul
#pragma unroll
  for (int it = 0; it < 32; ++it) {
    int idx = it * 256 + tid;          // 0..8191 (64 rows x 128 chunks)
    int lr = idx >> 7;
    int ch = idx & 127;
    int g = lr >> 4, ul = lr & 15;
    const u16* src = Wht + (size_t)(g * 1024 + u0 + ul) * 1024 + ch * 8;
    s16x8 v = *(const s16x8*)src;
    int dstB = lr * 2048 + ((ch * 16) ^ ((lr & 7) << 4));
    *(s16x8*)((char*)sWh + dstB) = v;
  }

  const int b0 = tid >> 4, ulT = tid & 15, uT = u0 + ulT;
  float cellR = encc[b0 * 1024 + uT];
  float holdR = ench[b0 * 1024 + uT];
  float bn_s = gamma[uT] * rsqrtf(mvar[uT] + 1e-3f);
  float bn_b = beta[uT] - mmean[uT] * bn_s;

  // publish initial h slice (from ench) into buf0 via relaxed atomics
  if (tid < 128) {
    int b = tid >> 3, j = tid & 7;
    u16 lo = f2bf(ench[b * 1024 + u0 + 2 * j]);
    u16 hi = f2bf(ench[b * 1024 + u0 + 2 * j + 1]);
    u32 val = (u32)lo | ((u32)hi << 16);
    __hip_atomic_store(hbuf32 + b * 512 + (u0 >> 1) + j, val,
                       __ATOMIC_RELAXED, __HIP_MEMORY_SCOPE_AGENT);
  }
  asm volatile("s_waitcnt vmcnt(0)" ::: "memory");
  __syncthreads();

  // prefetch xg(0) and inputs(0) into registers (plain cached loads)
  const size_t bstride = (size_t)128 * 4096;
  const float* xbase = xg + (size_t)(kh * 4) * bstride + wv * 1024 + u0 + ln;
  float xgr0, xgr1, xgr2, xgr3;
  int inpv;

  int arrived_old = -1;
  if (tid == 0)
    arrived_old = __hip_atomic_fetch_add(cnt, 1, __ATOMIC_RELAXED, __HIP_MEMORY_SCOPE_AGENT);
  xgr0 = xbase[0];
  xgr1 = xbase[bstride];
  xgr2 = xbase[2 * bstride];
  xgr3 = xbase[3 * bstride];
  inpv = inputs[b0 * 128];
  if (tid == 0 && arrived_old != 63) {
    int c = 0;
    while (__hip_atomic_load((const int*)cnt, __ATOMIC_RELAXED, __HIP_MEMORY_SCOPE_AGENT) < 64) {
      if (++c > (1 << 18)) break;   // safety: never hang the harness
    }
  }
  __syncthreads();
  asm volatile("" ::: "memory");

  const int lr = wv * 16 + ln;
  const int swzrow = lr * 2048;
  const int swzx = (lr & 7) << 4;

  for (int s = 0; s < 128; ++s) {
    const u64* hq = (const u64*)((const char*)hbuf32 + (s & 1) * 32768) +
                    (ln * 1024 + kh * 8) / 4;  // u64 index: 2048B-per-row / 8
    // two accumulator chains; A-fragments via relaxed atomic u64 loads (L2-bypass)
    f32x4 acc0 = {0.f, 0.f, 0.f, 0.f};
    f32x4 acc1 = {0.f, 0.f, 0.f, 0.f};
#pragma unroll 8
    for (int kt = 0; kt < 32; kt += 2) {
      union { u64 q[2]; s16x8 v; } a0u, a1u;
      const u64* p0 = hq + kt * 8;           // kt*32 u16 = kt*8 u64
      a0u.q[0] = __hip_atomic_load(p0, __ATOMIC_RELAXED, __HIP_MEMORY_SCOPE_AGENT);
      a0u.q[1] = __hip_atomic_load(p0 + 1, __ATOMIC_RELAXED, __HIP_MEMORY_SCOPE_AGENT);
      s16x8 b0v = *(const s16x8*)((const char*)sWh + swzrow + ((kt * 64 + kh * 16) ^ swzx));
      acc0 = __builtin_amdgcn_mfma_f32_16x16x32_bf16(a0u.v, b0v, acc0, 0, 0, 0);
      const u64* p1 = hq + (kt + 1) * 8;
      a1u.q[0] = __hip_atomic_load(p1, __ATOMIC_RELAXED, __HIP_MEMORY_SCOPE_AGENT);
      a1u.q[1] = __hip_atomic_load(p1 + 1, __ATOMIC_RELAXED, __HIP_MEMORY_SCOPE_AGENT);
      s16x8 b1v = *(const s16x8*)((const char*)sWh + swzrow + (((kt + 1) * 64 + kh * 16) ^ swzx));
      acc1 = __builtin_amdgcn_mfma_f32_16x16x32_bf16(a1u.v, b1v, acc1, 0, 0, 0);
    }
    f32x4 accs = acc0 + acc1;
    zx[wv][kh * 4 + 0][ln] = accs[0] + xgr0;
    zx[wv][kh * 4 + 1][ln] = accs[1] + xgr1;
    zx[wv][kh * 4 + 2][ln] = accs[2] + xgr2;
    zx[wv][kh * 4 + 3][ln] = accs[3] + xgr3;
    __syncthreads();
    {
      float zi = zx[0][b0][ulT], zf = zx[1][b0][ulT];
      float zc = zx[2][b0][ulT], zo = zx[3][b0][ulT];
      float ig = 1.f / (1.f + __expf(-zi));
      float fg = 1.f / (1.f + __expf(-zf));
      float og = 1.f / (1.f + __expf(-zo));
      float cc = fmaxf(zc, 0.f);
      float cnew = fg * cellR + ig * cc;
      float hnew = og * fmaxf(cnew, 0.f);
      if (inpv == 0) { cnew = cellR; hnew = holdR; }
      cellR = cnew;
      holdR = hnew;
      u16 hb = f2bf(hnew);
      sh[b0][ulT] = hb;
      hbn[(size_t)(b0 * 128 + s) * 1024 + uT] = f2bf(hnew * bn_s + bn_b);
    }
    if (s < 127) {
      __syncthreads();
      // publish h^(s+1) slice via relaxed atomic u32 stores
      if (tid < 128) {
        int b = tid >> 3, j = tid & 7;
        u32 val = (u32)sh[b][2 * j] | ((u32)sh[b][2 * j + 1] << 16);
        __hip_atomic_store(hbuf32 + ((s + 1) & 1) * 8192 + b * 512 + (u0 >> 1) + j, val,
                           __ATOMIC_RELAXED, __HIP_MEMORY_SCOPE_AGENT);
      }
      asm volatile("s_waitcnt vmcnt(0)" ::: "memory");
      __syncthreads();
      const int target = (s + 2) * 64;
      int old = -1;
      if (tid == 0)
        old = __hip_atomic_fetch_add(cnt, 1, __ATOMIC_RELAXED, __HIP_MEMORY_SCOPE_AGENT);
      // prefetch next step's xg and mask (cached loads) between arrive and wait
      const float* xb = xbase + (s + 1) * 4096;
      xgr0 = xb[0];
      xgr1 = xb[bstride];
      xgr2 = xb[2 * bstride];
      xgr3 = xb[3 * bstride];
      inpv = inputs[b0 * 128 + s + 1];
      if (tid == 0 && old != target - 1) {
        int c = 0;
        while (__hip_atomic_load((const int*)cnt, __ATOMIC_RELAXED, __HIP_MEMORY_SCOPE_AGENT) < target) {
          if (++c > (1 << 18)) break;   // safety: never hang the harness
        }
      }
      __syncthreads();
      asm volatile("" ::: "memory");
    }
  }
}

// ---------- softmax finish ----------

__global__ void rcp_kernel(float* rs) {
  int i = blockIdx.x * 256 + threadIdx.x;   // 2048 threads
  rs[i] = 1.0f / rs[i];
}

__global__ void scale_kernel(float* __restrict__ out, const float* __restrict__ rinv) {
  const int total4 = 16384000;              // 65,536,000 / 4
  for (int i = blockIdx.x * 256 + threadIdx.x; i < total4; i += gridDim.x * 256) {
    float4* p = (float4*)out + i;
    float4 v = *p;
    int row = i / 8000;                     // 8000 float4 per row
    float sF = rinv[row];
    v.x *= sF; v.y *= sF; v.z *= sF; v.w *= sF;
    *p = v;
  }
}

// ---------- launch ----------

extern "C" void kernel_launch(void* const* d_in, const int* in_sizes, int n_in,
                              void* d_out, int out_size, void* d_ws, size_t ws_size,
                              hipStream_t stream) {
  (void)in_sizes; (void)n_in; (void)out_size;
  const int*   inputs = (const int*)d_in[0];
  const float* ench   = (const float*)d_in[1];
  const float* encc   = (const float*)d_in[2];
  const float* emb    = (const float*)d_in[3];
  const float* Wx     = (const float*)d_in[4];
  const float* Wh     = (const float*)d_in[5];
  const float* bb     = (const float*)d_in[6];
  const float* gamma  = (const float*)d_in[7];
  const float* beta   = (const float*)d_in[8];
  const float* mmean  = (const float*)d_in[9];
  const float* mvar   = (const float*)d_in[10];
  const float* W1     = (const float*)d_in[11];
  const float* b1     = (const float*)d_in[12];
  const float* W2     = (const float*)d_in[13];
  const float* b2     = (const float*)d_in[14];
  float* out = (float*)d_out;

  char* p = (char*)d_ws;
  size_t off = 0;
  int*   cnt    = (int*)(p + 0);            // word 0
  float* rowsum = (float*)(p + 1024);       // 2048 floats; memset covers [0,9216)
  off = 16384;
  u32*   hbuf32 = (u32*)(p + off);   off += 2 * 16 * 512 * 4;           // 64KB
  off = 81920;
  u16*   xbf  = (u16*)(p + off);     off += (size_t)2048 * 512 * 2;     // 2MB
  u16*   Wxt  = (u16*)(p + off);     off += (size_t)4096 * 512 * 2;     // 4MB
  u16*   Wht  = (u16*)(p + off);     off += (size_t)4096 * 1024 * 2;    // 8MB
  u16*   W1t  = (u16*)(p + off);     off += (size_t)1024 * 1024 * 2;    // 2MB
  u16*   W2t  = (u16*)(p + off);     off += (size_t)32000 * 1024 * 2;   // 64MB
  float* xg   = (float*)(p + off);   off += (size_t)2048 * 4096 * 4;    // 32MB
  u16*   hbn  = (u16*)(p + off);     off += (size_t)2048 * 1024 * 2;    // 4MB
  u16*   d1   = (u16*)(p + off);     off += (size_t)2048 * 1024 * 2;    // 4MB
  if (ws_size < off) return;  // insufficient scratch; avoid OOB

  hipMemsetAsync(d_ws, 0, 9216, stream);  // cnt + rowsum

  embed_kernel<<<512, 256, 0, stream>>>(inputs, emb, xbf);
  transpose_bf16<<<(512 / 32) * (4096 / 32), 256, 0, stream>>>(Wx, Wxt, 512, 4096);
  transpose_bf16<<<(1024 / 32) * (4096 / 32), 256, 0, stream>>>(Wh, Wht, 1024, 4096);
  transpose_bf16<<<(1024 / 32) * (1024 / 32), 256, 0, stream>>>(W1, W1t, 1024, 1024);
  transpose_bf16<<<(1024 / 32) * (32000 / 32), 256, 0, stream>>>(W2, W2t, 1024, 32000);

  gemm_bf16<0><<<16 * 32, 256, 0, stream>>>(xbf, Wxt, bb, xg, nullptr, 2048, 4096, 512);

  lstm_kernel<<<64, 256, 0, stream>>>(xg, Wht, inputs, ench, encc, gamma, beta,
                                      mmean, mvar, hbuf32, hbn, cnt);

  gemm_bf16<1><<<16 * 8, 256, 0, stream>>>(hbn, W1t, b1, d1, nullptr, 2048, 1024, 1024);
  gemm_bf16<2><<<16 * 250, 256, 0, stream>>>(d1, W2t, b2, out, rowsum, 2048, 32000, 1024);

  rcp_kernel<<<8, 256, 0, stream>>>(rowsum);
  scale_kernel<<<2048, 256, 0, stream>>>(out, rowsum);
}